// Round 1
// baseline (569.941 us; speedup 1.0000x reference)
//
#include <hip/hip_runtime.h>

#define VOCAB 32000
#define DIM   128
#define BATCH 1024
#define CTX   10

// ---------------------------------------------------------------------------
// Kernel A: extract one-hot index per (b,c) row. 1.31 GB read, HBM-bound.
// Exactly one nonzero per row -> exactly one write per row, race-free.
// ---------------------------------------------------------------------------
__global__ __launch_bounds__(256) void onehot_idx_kernel(
    const float* __restrict__ batch, int* __restrict__ idx) {
    const unsigned int total4 = (unsigned int)BATCH * CTX * (VOCAB / 4); // 81,920,000
    const unsigned int stride = gridDim.x * blockDim.x;
    for (unsigned int i = blockIdx.x * blockDim.x + threadIdx.x; i < total4; i += stride) {
        float4 v = reinterpret_cast<const float4*>(batch)[i];
        if (v.x != 0.f || v.y != 0.f || v.z != 0.f || v.w != 0.f) {
            unsigned int e   = i * 4u;            // flat element index (< 2^32)
            unsigned int row = e / VOCAB;         // (b*CTX + c)
            unsigned int col = e - row * VOCAB;   // v base (VOCAB % 4 == 0)
            if      (v.x != 0.f) idx[row] = (int)col;
            else if (v.y != 0.f) idx[row] = (int)col + 1;
            else if (v.z != 0.f) idx[row] = (int)col + 2;
            else                 idx[row] = (int)col + 3;
        }
    }
}

// ---------------------------------------------------------------------------
// Kernel B: avg[b][d] = mean_c emb[idx[b][c]][d]. 1024 blocks x 128 threads.
// ---------------------------------------------------------------------------
__global__ __launch_bounds__(128) void avg_emb_kernel(
    const int* __restrict__ idx, const float* __restrict__ emb,
    float* __restrict__ avg) {
    int b = blockIdx.x;
    int d = threadIdx.x;
    float s = 0.f;
#pragma unroll
    for (int c = 0; c < CTX; ++c) {
        int id = idx[b * CTX + c];            // block-uniform -> scalar load
        s += emb[id * DIM + d];               // coalesced 512B gather per wave
    }
    avg[b * DIM + d] = s * (1.f / CTX);
}

// ---------------------------------------------------------------------------
// Kernel C: logits = avg @ w_out. f32 vector FMA (no f32-input MFMA on CDNA4).
// Block: 256 threads = 256 consecutive n (coalesced w_out), 64 rows m.
// avg[] indices are block-uniform -> compiler emits s_load -> SGPR-operand FMA.
// Writes logits into d_out (softmax kernel then works in place).
// ---------------------------------------------------------------------------
__global__ __launch_bounds__(256) void gemm_kernel(
    const float* __restrict__ avg, const float* __restrict__ w,
    float* __restrict__ out) {
    const int n  = blockIdx.x * 256 + threadIdx.x;
    const int m0 = blockIdx.y * 64;
    float acc[64];
#pragma unroll
    for (int m = 0; m < 64; ++m) acc[m] = 0.f;

#pragma unroll 1   // keep body ~one d-chunk so it fits I-cache (512 FMA/iter)
    for (int d0 = 0; d0 < DIM; d0 += 8) {
        float wv[8];
#pragma unroll
        for (int j = 0; j < 8; ++j) wv[j] = w[(d0 + j) * VOCAB + n];
#pragma unroll
        for (int m = 0; m < 64; ++m) {
#pragma unroll
            for (int j = 0; j < 8; ++j)
                acc[m] = fmaf(avg[(m0 + m) * DIM + d0 + j], wv[j], acc[m]);
        }
    }
#pragma unroll
    for (int m = 0; m < 64; ++m)
        out[(m0 + m) * VOCAB + n] = acc[m];
}

// ---------------------------------------------------------------------------
// Kernel D: in-place row softmax over d_out. One block per row; 3 passes
// (max / sum-exp / normalize); row is 128 KB so passes 2-3 mostly hit L2.
// ---------------------------------------------------------------------------
__global__ __launch_bounds__(256) void softmax_kernel(float* __restrict__ out) {
    float* p = out + (long long)blockIdx.x * VOCAB;
    const int tid = threadIdx.x;
    __shared__ float red[256];

    // pass 1: row max
    float m = -INFINITY;
    for (int i = tid; i < VOCAB / 4; i += 256) {
        float4 v = reinterpret_cast<float4*>(p)[i];
        m = fmaxf(m, fmaxf(fmaxf(v.x, v.y), fmaxf(v.z, v.w)));
    }
    red[tid] = m;
    __syncthreads();
    for (int s = 128; s > 0; s >>= 1) {
        if (tid < s) red[tid] = fmaxf(red[tid], red[tid + s]);
        __syncthreads();
    }
    m = red[0];
    __syncthreads();

    // pass 2: sum of exp
    float sum = 0.f;
    for (int i = tid; i < VOCAB / 4; i += 256) {
        float4 v = reinterpret_cast<float4*>(p)[i];
        sum += expf(v.x - m) + expf(v.y - m) + expf(v.z - m) + expf(v.w - m);
    }
    red[tid] = sum;
    __syncthreads();
    for (int s = 128; s > 0; s >>= 1) {
        if (tid < s) red[tid] += red[tid + s];
        __syncthreads();
    }
    float inv = 1.f / red[0];
    __syncthreads();

    // pass 3: normalize + write
    for (int i = tid; i < VOCAB / 4; i += 256) {
        float4 v = reinterpret_cast<float4*>(p)[i];
        float4 o;
        o.x = expf(v.x - m) * inv;
        o.y = expf(v.y - m) * inv;
        o.z = expf(v.z - m) * inv;
        o.w = expf(v.w - m) * inv;
        reinterpret_cast<float4*>(p)[i] = o;
    }
}

// ---------------------------------------------------------------------------
extern "C" void kernel_launch(void* const* d_in, const int* in_sizes, int n_in,
                              void* d_out, int out_size, void* d_ws, size_t ws_size,
                              hipStream_t stream) {
    const float* batch = (const float*)d_in[0];  // [1024,10,32000] f32
    const float* emb   = (const float*)d_in[1];  // [32000,128]     f32
    const float* w_out = (const float*)d_in[2];  // [128,32000]     f32
    float*       out   = (float*)d_out;          // [1024,32000]    f32

    int*   idx = (int*)d_ws;                                   // 40 KB
    float* avg = (float*)((char*)d_ws + BATCH * CTX * sizeof(int)); // 512 KB

    onehot_idx_kernel<<<2048, 256, 0, stream>>>(batch, idx);
    avg_emb_kernel<<<BATCH, DIM, 0, stream>>>(idx, emb, avg);
    gemm_kernel<<<dim3(VOCAB / 256, BATCH / 64), 256, 0, stream>>>(avg, w_out, out);
    softmax_kernel<<<BATCH, 256, 0, stream>>>(out);
}